// Round 3
// baseline (178.957 us; speedup 1.0000x reference)
//
#include <hip/hip_runtime.h>
#include <math.h>

#define T_SEQ 2048
#define NH    12
#define NB    2
#define BHC   (NB*NH)        // 24
#define NQT   32             // 2048/64

typedef _Float16 half4_t __attribute__((ext_vector_type(4)));
typedef _Float16 half8_t __attribute__((ext_vector_type(8)));
typedef float    floatx4 __attribute__((ext_vector_type(4)));

__device__ __forceinline__ half8_t h8splat(_Float16 s) {
  return (half8_t){s, s, s, s, s, s, s, s};
}

// ---------------- prep: f16 frag-order Q_aug/K_aug/V + premultiplied bias ----------------
// QF/KF chunk (tile16, dp, lane): row = tile16*16 + ln, d = dp*32 + quad*8 + j  (x32 frag order)
// VF chunk (tile64, v2, nt, lane): d = nt*16 + ln, key = tile64*64 + v2*32 + quad*4 + {j,16+j} (x16)
// NOTE: log2(e) is folded into the Q-side scales and into the bias premult, so the
// flash kernel's softmax runs entirely in the exp2 domain (raw v_exp_f32, no muls).
__global__ __launch_bounds__(256) void prep_kernel(
    const float* __restrict__ Q, const float* __restrict__ K,
    const float* __restrict__ V, const float* __restrict__ W,
    const float* __restrict__ wstd, const float* __restrict__ wrec,
    const float* __restrict__ dbias, const float* __restrict__ wdisc,
    ushort* __restrict__ QF, ushort* __restrict__ KF, ushort* __restrict__ VF,
    float* __restrict__ B2)
{
  __shared__ __align__(16) _Float16 Qsh[64*72];   // 144B row stride
  __shared__ __align__(16) _Float16 Ksh[64*72];
  __shared__ __align__(16) _Float16 Vsh[64*72];
  __shared__ __align__(16) _Float16 Lqh[64*16];
  __shared__ __align__(16) _Float16 Lkh[64*16];

  const int tid = threadIdx.x;
  const int w = tid >> 6, lane = tid & 63;
  const int quad = lane >> 4, ln = lane & 15;
  const int bh = blockIdx.x >> 5, tblk = blockIdx.x & 31;
  const long g0 = ((long)bh * T_SEQ + tblk * 64) * 64;

  const float4* gQ = (const float4*)(Q + g0);
  const float4* gK = (const float4*)(K + g0);
  const float4* gV = (const float4*)(V + g0);
  for (int i = tid; i < 1024; i += 256) {
    int r = i >> 4, c4 = i & 15;
    float4 q = gQ[i], k = gK[i], v = gV[i];
    *(half4_t*)&Qsh[r*72 + c4*4] = (half4_t){(_Float16)q.x,(_Float16)q.y,(_Float16)q.z,(_Float16)q.w};
    *(half4_t*)&Ksh[r*72 + c4*4] = (half4_t){(_Float16)k.x,(_Float16)k.y,(_Float16)k.z,(_Float16)k.w};
    *(half4_t*)&Vsh[r*72 + c4*4] = (half4_t){(_Float16)v.x,(_Float16)v.y,(_Float16)v.z,(_Float16)v.w};
  }
  __syncthreads();

  half4_t bw[4];
#pragma unroll
  for (int dk = 0; dk < 4; dk++)
#pragma unroll
    for (int i = 0; i < 4; i++)
      bw[dk][i] = (_Float16)W[(dk*16 + quad*4 + i)*16 + ln];

  floatx4 cq = {0.f,0.f,0.f,0.f}, ck = {0.f,0.f,0.f,0.f};
#pragma unroll
  for (int dk = 0; dk < 4; dk++) {
    half4_t aq = *(const half4_t*)&Qsh[(w*16 + ln)*72 + dk*16 + quad*4];
    half4_t ak = *(const half4_t*)&Ksh[(w*16 + ln)*72 + dk*16 + quad*4];
    cq = __builtin_amdgcn_mfma_f32_16x16x16f16(aq, bw[dk], cq, 0, 0, 0);
    ck = __builtin_amdgcn_mfma_f32_16x16x16f16(ak, bw[dk], ck, 0, 0, 0);
  }
#pragma unroll
  for (int i = 0; i < 4; i++) {            // C: row = 16w+quad*4+i, col = ln
    Lqh[(w*16 + quad*4 + i)*16 + ln] = (_Float16)cq[i];
    Lkh[(w*16 + quad*4 + i)*16 + ln] = (_Float16)ck[i];
  }
  __syncthreads();

  const int h = bh % NH;
  const float LOG2E = 1.4426950408889634f;
  const float sstd = sqrtf(wstd[h]);
  const float srec = sqrtf(wrec[h]);
  const half8_t hq_std = h8splat((_Float16)(0.125f * sstd * LOG2E));  // 1/sqrt(64) + log2e folded
  const half8_t hk_std = h8splat((_Float16)sstd);
  const half8_t hq_rec = h8splat((_Float16)(0.125f * srec * LOG2E));
  const half8_t hk_rec = h8splat((_Float16)srec);

  // premultiplied bias (log2 domain)
  if (tid < 64) B2[(long)bh*T_SEQ + tblk*64 + tid] =
      LOG2E * wdisc[h] * dbias[(long)bh*T_SEQ + tblk*64 + tid];

#pragma unroll
  for (int cc = 0; cc < 2; cc++) {
    int c = tid + cc * 256;                // chunk 0..511
    {
      int lp = c & 63, dp = (c >> 6) & 1, rt = c >> 7;
      int row = rt*16 + (lp & 15);
      int d0 = dp*32 + (lp >> 4)*8;        // 48-boundary on chunk boundary
      half8_t hq, hk;
      if (d0 < 48) {
        hq = *(const half8_t*)&Qsh[row*72 + d0] * hq_std;
        hk = *(const half8_t*)&Ksh[row*72 + d0] * hk_std;
      } else {
        hq = *(const half8_t*)&Lkh[row*16 + (d0-48)] * hq_rec;  // Q_aug gets K_low
        hk = *(const half8_t*)&Lqh[row*16 + (d0-48)] * hk_rec;  // K_aug gets Q_low
      }
      long tile16 = (long)bh*128 + tblk*4 + rt;
      ((int4*)QF)[tile16*128 + dp*64 + lp] = *(int4*)&hq;
      ((int4*)KF)[tile16*128 + dp*64 + lp] = *(int4*)&hk;
    }
    {
      int lv = c & 63, nt = (c >> 6) & 3, v2 = c >> 8;
      int d = nt*16 + (lv & 15), qv = lv >> 4;
      half8_t hv;
#pragma unroll
      for (int j = 0; j < 4; j++) {
        hv[j]   = Vsh[(v2*32 + qv*4 + j)*72 + d];
        hv[4+j] = Vsh[(v2*32 + 16 + qv*4 + j)*72 + d];
      }
      ((int4*)VF)[((long)bh*32 + tblk)*512 + (v2*4 + nt)*64 + lv] = *(int4*)&hv;
    }
  }
}

// ---------------- flash: 2-wave split-K, TWO adjacent q-tiles per wave ----------------
// Rounds 0 and 2 both measured 44 us with identical L2 traffic (830 MB of K/V
// fragment re-reads) despite a 2x occupancy difference -> L2-BW-bound.
// Each wave now amortizes every kf/vf load over two adjacent 16-row q-tiles
// (t16 = 2p, 2p+1; adjacent pairing keeps ktmax identical for both), halving
// K/V L2 traffic. Split-K across the 2 waves retained; LDS merge at the end.
// launch_bounds min-waves=3 (VGPR cap ~170): round-1's (128,6) squeezed the
// allocator to 40 VGPRs and spilled -> 930 MB/dispatch scratch. DO NOT tighten.
__global__ __launch_bounds__(128, 3) void flash_kernel(
    const ushort* __restrict__ QF, const ushort* __restrict__ KF,
    const ushort* __restrict__ VF, const float* __restrict__ B2,
    float* __restrict__ Out)
{
  __shared__ float sm1[2][16];
  __shared__ float sl1[2][16];
  __shared__ float sacc1[2][64*16];

  const int tid  = threadIdx.x;
  const int wv   = tid >> 6;               // 0 or 1
  const int lane = tid & 63;
  const int quad = lane >> 4, ln = lane & 15;
  const int bid = blockIdx.x;
  const int bh  = bid % BHC;               // same bh -> same XCD (24 % 8 == 0)
  const int p   = 63 - bid / BHC;          // heavy q-pairs first
  const int t16a = 2*p;                    // q-tiles 2p, 2p+1
  const int qa = t16a*16 + ln;             // tile-A q-row for this lane
  const int qb = qa + 16;                  // tile-B q-row
  const int ktmax = p >> 1;                // same for both tiles of the pair

  const ushort* gK = KF + (long)bh * 131072;   // halves
  const ushort* gV = VF + (long)bh * 131072;
  const float*  gB = B2 + (long)bh * T_SEQ;

  // Q B-frags for both tiles (x32 layout: d = quad*8+j per 32-slice)
  half8_t bqa[2], bqb[2];
  {
    const ushort* gQ = QF + ((long)bh*128 + t16a) * 1024;
    bqa[0] = *(const half8_t*)(gQ + lane*8);
    bqa[1] = *(const half8_t*)(gQ + 512 + lane*8);
    bqb[0] = *(const half8_t*)(gQ + 1024 + lane*8);
    bqb[1] = *(const half8_t*)(gQ + 1536 + lane*8);
  }

  float mA = -1e30f, lA = 0.f, mB = -1e30f, lB = 0.f;
  floatx4 accA[4], accB[4];
#pragma unroll
  for (int nt = 0; nt < 4; nt++) {
    accA[nt] = (floatx4){0.f,0.f,0.f,0.f};
    accB[nt] = (floatx4){0.f,0.f,0.f,0.f};
  }

  // prologue: this wave's first tile into registers (clamped if out of range)
  const int kt0 = wv;
  const long oo0 = (long)(kt0 <= ktmax ? kt0 : 0) * 4096;
  half8_t kf[8], vf[8];
#pragma unroll
  for (int c = 0; c < 8; c++) {
    kf[c] = *(const half8_t*)(gK + oo0 + c*512 + lane*8);
    vf[c] = *(const half8_t*)(gV + oo0 + c*512 + lane*8);
  }

  for (int kt = kt0; kt <= ktmax; kt += 2) {
    // next-tile offset (stride 2; last iter redundantly reloads current — L2 hit)
    const long onx = (long)(kt + 2 <= ktmax ? kt + 2 : kt) * 4096;

    // bias registers (shared by both q-tiles; hoisted so their wait doesn't
    // drain the kf prefetch below)
    float4 bb[4];
#pragma unroll
    for (int mt = 0; mt < 4; mt++)
      bb[mt] = *(const float4*)(gB + kt*64 + mt*16 + quad*4);  // quad-uniform

    // ---- S^T = K_aug·Q_aug^T for both tiles (x32):
    // st[mt][i] = S[q-row][key = kt*64 + mt*16 + quad*4 + i]
    floatx4 sta[4], stb[4];
#pragma unroll
    for (int mt = 0; mt < 4; mt++) {
      floatx4 ca = (floatx4){0.f,0.f,0.f,0.f};
      ca = __builtin_amdgcn_mfma_f32_16x16x32_f16(kf[mt*2],     bqa[0], ca, 0, 0, 0);
      ca = __builtin_amdgcn_mfma_f32_16x16x32_f16(kf[mt*2 + 1], bqa[1], ca, 0, 0, 0);
      sta[mt] = ca;
      floatx4 cb = (floatx4){0.f,0.f,0.f,0.f};
      cb = __builtin_amdgcn_mfma_f32_16x16x32_f16(kf[mt*2],     bqb[0], cb, 0, 0, 0);
      cb = __builtin_amdgcn_mfma_f32_16x16x32_f16(kf[mt*2 + 1], bqb[1], cb, 0, 0, 0);
      stb[mt] = cb;
    }
    // kf dead -> rotate in next tile's K frags (landing hidden behind softmax+PV)
#pragma unroll
    for (int c = 0; c < 8; c++)
      kf[c] = *(const half8_t*)(gK + onx + c*512 + lane*8);

    const bool diag = (kt == ktmax);

    // ---- softmax tile A (exp2 domain; one q-row per lane) ----
    half4_t paA[4], paB[4];
    {
      float rowmax = -1e30f;
#pragma unroll
      for (int mt = 0; mt < 4; mt++)
#pragma unroll
        for (int i = 0; i < 4; i++) {
          float v = sta[mt][i] + ((const float*)&bb[mt])[i];
          int key = kt*64 + mt*16 + quad*4 + i;
          if (diag && key > qa) v = -1e30f;
          sta[mt][i] = v;
          rowmax = fmaxf(rowmax, v);
        }
      rowmax = fmaxf(rowmax, __shfl_xor(rowmax, 16));
      rowmax = fmaxf(rowmax, __shfl_xor(rowmax, 32));
      if (!__all(rowmax <= mA + 8.f)) {     // defer-rescale (P bounded by 2^8)
        float mnew  = fmaxf(mA, rowmax);
        float alpha = exp2f(mA - mnew);
        float af[4];
#pragma unroll
        for (int i = 0; i < 4; i++) af[i] = __shfl(alpha, quad*4 + i);
#pragma unroll
        for (int nt = 0; nt < 4; nt++)
#pragma unroll
          for (int i = 0; i < 4; i++) accA[nt][i] *= af[i];
        lA *= alpha;
        mA  = mnew;
      }
      float psum = 0.f;
#pragma unroll
      for (int mt = 0; mt < 4; mt++)
#pragma unroll
        for (int i = 0; i < 4; i++) {
          float pv = exp2f(sta[mt][i] - mA);
          psum += pv;
          paA[mt][i] = (_Float16)pv;
        }
      psum += __shfl_xor(psum, 16);
      psum += __shfl_xor(psum, 32);
      lA += psum;
    }

    // ---- softmax tile B ----
    {
      float rowmax = -1e30f;
#pragma unroll
      for (int mt = 0; mt < 4; mt++)
#pragma unroll
        for (int i = 0; i < 4; i++) {
          float v = stb[mt][i] + ((const float*)&bb[mt])[i];
          int key = kt*64 + mt*16 + quad*4 + i;
          if (diag && key > qb) v = -1e30f;
          stb[mt][i] = v;
          rowmax = fmaxf(rowmax, v);
        }
      rowmax = fmaxf(rowmax, __shfl_xor(rowmax, 16));
      rowmax = fmaxf(rowmax, __shfl_xor(rowmax, 32));
      if (!__all(rowmax <= mB + 8.f)) {
        float mnew  = fmaxf(mB, rowmax);
        float alpha = exp2f(mB - mnew);
        float af[4];
#pragma unroll
        for (int i = 0; i < 4; i++) af[i] = __shfl(alpha, quad*4 + i);
#pragma unroll
        for (int nt = 0; nt < 4; nt++)
#pragma unroll
          for (int i = 0; i < 4; i++) accB[nt][i] *= af[i];
        lB *= alpha;
        mB  = mnew;
      }
      float psum = 0.f;
#pragma unroll
      for (int mt = 0; mt < 4; mt++)
#pragma unroll
        for (int i = 0; i < 4; i++) {
          float pv = exp2f(stb[mt][i] - mB);
          psum += pv;
          paB[mt][i] = (_Float16)pv;
        }
      psum += __shfl_xor(psum, 16);
      psum += __shfl_xor(psum, 32);
      lB += psum;
    }

    // ---- O += P·V for both tiles (x16; P stays in registers) ----
#pragma unroll
    for (int v2 = 0; v2 < 2; v2++)
#pragma unroll
      for (int nt = 0; nt < 4; nt++) {
        half8_t vv = vf[v2*4 + nt];
        half4_t b0 = __builtin_shufflevector(vv, vv, 0,1,2,3);
        half4_t b1 = __builtin_shufflevector(vv, vv, 4,5,6,7);
        accA[nt] = __builtin_amdgcn_mfma_f32_16x16x16f16(paA[2*v2],   b0, accA[nt], 0, 0, 0);
        accA[nt] = __builtin_amdgcn_mfma_f32_16x16x16f16(paA[2*v2+1], b1, accA[nt], 0, 0, 0);
        accB[nt] = __builtin_amdgcn_mfma_f32_16x16x16f16(paB[2*v2],   b0, accB[nt], 0, 0, 0);
        accB[nt] = __builtin_amdgcn_mfma_f32_16x16x16f16(paB[2*v2+1], b1, accB[nt], 0, 0, 0);
      }
    // vf dead -> rotate in next tile's V frags (landing hidden behind next QK+softmax)
#pragma unroll
    for (int c = 0; c < 8; c++)
      vf[c] = *(const half8_t*)(gV + onx + c*512 + lane*8);
  }

  // ---- cross-wave merge + epilogue (per q-tile) ----
  if (wv == 1) {
    if (quad == 0) {
      sm1[0][ln] = mA; sl1[0][ln] = lA;
      sm1[1][ln] = mB; sl1[1][ln] = lB;
    }
#pragma unroll
    for (int nt = 0; nt < 4; nt++)
#pragma unroll
      for (int i = 0; i < 4; i++) {
        sacc1[0][lane*16 + nt*4 + i] = accA[nt][i];
        sacc1[1][lane*16 + nt*4 + i] = accB[nt][i];
      }
  }
  __syncthreads();
  if (wv == 0) {
#pragma unroll
    for (int t = 0; t < 2; t++) {
      const float m0v = (t == 0) ? mA : mB;
      const float l0v = (t == 0) ? lA : lB;
      const floatx4* acc0 = (t == 0) ? accA : accB;
      const float m1v = sm1[t][ln];
      const float l1v = sl1[t][ln];
      const float mm  = fmaxf(m0v, m1v);
      const float w0  = exp2f(m0v - mm);   // w1=0 when wave1 had no tiles (m1=-1e30)
      const float w1  = exp2f(m1v - mm);
      const float lm  = l0v * w0 + l1v * w1;
      float w0r[4], w1r[4], lr[4];
#pragma unroll
      for (int i = 0; i < 4; i++) {
        w0r[i] = __shfl(w0, quad*4 + i);
        w1r[i] = __shfl(w1, quad*4 + i);
        lr[i]  = 1.f / __shfl(lm, quad*4 + i);
      }
      const long obase = (long)bh*T_SEQ*64 + (long)((t16a + t)*16)*64;
#pragma unroll
      for (int i = 0; i < 4; i++)
#pragma unroll
        for (int nt = 0; nt < 4; nt++) {
          float4 a1 = *(const float4*)&sacc1[t][lane*16 + nt*4];
          Out[obase + (quad*4 + i)*64 + nt*16 + ln] =
              (acc0[nt][i]*w0r[i] + ((const float*)&a1)[i]*w1r[i]) * lr[i];
        }
    }
  }
}

extern "C" void kernel_launch(void* const* d_in, const int* in_sizes, int n_in,
                              void* d_out, int out_size, void* d_ws, size_t ws_size,
                              hipStream_t stream) {
  const float* Q     = (const float*)d_in[0];
  const float* K     = (const float*)d_in[1];
  const float* V     = (const float*)d_in[2];
  const float* dbias = (const float*)d_in[3];
  const float* W     = (const float*)d_in[4];
  const float* wstd  = (const float*)d_in[5];
  const float* wrec  = (const float*)d_in[6];
  const float* wdisc = (const float*)d_in[7];
  float* Out = (float*)d_out;

  const long NEL = (long)BHC * T_SEQ * 64;
  ushort* QF = (ushort*)d_ws;            // f16 x32-frag-order Q_aug (scales+log2e folded)
  ushort* KF = QF + NEL;                 // f16 x32-frag-order K_aug
  ushort* VF = KF + NEL;                 // f16 x16-frag-order V
  float*  B2 = (float*)(VF + NEL);       // premultiplied wd*dbias*log2e

  prep_kernel<<<BHC * NQT, 256, 0, stream>>>(Q, K, V, W, wstd, wrec, dbias, wdisc,
                                             QF, KF, VF, B2);
  flash_kernel<<<BHC * 64, 128, 0, stream>>>(QF, KF, VF, B2, Out);
}

// Round 4
// 136.543 us; speedup vs baseline: 1.3106x; 1.3106x over previous
//
#include <hip/hip_runtime.h>
#include <math.h>

#define T_SEQ 2048
#define NH    12
#define NB    2
#define BHC   (NB*NH)        // 24
#define NQT   32             // 2048/64

typedef _Float16 half4_t __attribute__((ext_vector_type(4)));
typedef _Float16 half8_t __attribute__((ext_vector_type(8)));
typedef float    floatx4 __attribute__((ext_vector_type(4)));

__device__ __forceinline__ half8_t h8splat(_Float16 s) {
  return (half8_t){s, s, s, s, s, s, s, s};
}

// async global -> LDS, 16B per lane; dst is wave-uniform base, lanes land at +lane*16
__device__ __forceinline__ void gload_lds16(const void* g, void* l) {
  __builtin_amdgcn_global_load_lds(
      (const __attribute__((address_space(1))) unsigned int*)g,
      (__attribute__((address_space(3))) unsigned int*)l, 16, 0, 0);
}

// ---------------- prep: f16 frag-order Q_aug/K_aug/V + premultiplied bias ----------------
// QF/KF chunk (tile16, dp, lane): row = tile16*16 + ln, d = dp*32 + quad*8 + j  (x32 frag order)
// VF chunk (tile64, v2, nt, lane): d = nt*16 + ln, key = tile64*64 + v2*32 + quad*4 + {j,16+j} (x16)
// NOTE: log2(e) is folded into the Q-side scales and into the bias premult, so the
// flash kernel's softmax runs entirely in the exp2 domain (raw v_exp_f32, no muls).
__global__ __launch_bounds__(256) void prep_kernel(
    const float* __restrict__ Q, const float* __restrict__ K,
    const float* __restrict__ V, const float* __restrict__ W,
    const float* __restrict__ wstd, const float* __restrict__ wrec,
    const float* __restrict__ dbias, const float* __restrict__ wdisc,
    ushort* __restrict__ QF, ushort* __restrict__ KF, ushort* __restrict__ VF,
    float* __restrict__ B2)
{
  __shared__ __align__(16) _Float16 Qsh[64*72];   // 144B row stride
  __shared__ __align__(16) _Float16 Ksh[64*72];
  __shared__ __align__(16) _Float16 Vsh[64*72];
  __shared__ __align__(16) _Float16 Lqh[64*16];
  __shared__ __align__(16) _Float16 Lkh[64*16];

  const int tid = threadIdx.x;
  const int w = tid >> 6, lane = tid & 63;
  const int quad = lane >> 4, ln = lane & 15;
  const int bh = blockIdx.x >> 5, tblk = blockIdx.x & 31;
  const long g0 = ((long)bh * T_SEQ + tblk * 64) * 64;

  const float4* gQ = (const float4*)(Q + g0);
  const float4* gK = (const float4*)(K + g0);
  const float4* gV = (const float4*)(V + g0);
  for (int i = tid; i < 1024; i += 256) {
    int r = i >> 4, c4 = i & 15;
    float4 q = gQ[i], k = gK[i], v = gV[i];
    *(half4_t*)&Qsh[r*72 + c4*4] = (half4_t){(_Float16)q.x,(_Float16)q.y,(_Float16)q.z,(_Float16)q.w};
    *(half4_t*)&Ksh[r*72 + c4*4] = (half4_t){(_Float16)k.x,(_Float16)k.y,(_Float16)k.z,(_Float16)k.w};
    *(half4_t*)&Vsh[r*72 + c4*4] = (half4_t){(_Float16)v.x,(_Float16)v.y,(_Float16)v.z,(_Float16)v.w};
  }
  __syncthreads();

  half4_t bw[4];
#pragma unroll
  for (int dk = 0; dk < 4; dk++)
#pragma unroll
    for (int i = 0; i < 4; i++)
      bw[dk][i] = (_Float16)W[(dk*16 + quad*4 + i)*16 + ln];

  floatx4 cq = {0.f,0.f,0.f,0.f}, ck = {0.f,0.f,0.f,0.f};
#pragma unroll
  for (int dk = 0; dk < 4; dk++) {
    half4_t aq = *(const half4_t*)&Qsh[(w*16 + ln)*72 + dk*16 + quad*4];
    half4_t ak = *(const half4_t*)&Ksh[(w*16 + ln)*72 + dk*16 + quad*4];
    cq = __builtin_amdgcn_mfma_f32_16x16x16f16(aq, bw[dk], cq, 0, 0, 0);
    ck = __builtin_amdgcn_mfma_f32_16x16x16f16(ak, bw[dk], ck, 0, 0, 0);
  }
#pragma unroll
  for (int i = 0; i < 4; i++) {            // C: row = 16w+quad*4+i, col = ln
    Lqh[(w*16 + quad*4 + i)*16 + ln] = (_Float16)cq[i];
    Lkh[(w*16 + quad*4 + i)*16 + ln] = (_Float16)ck[i];
  }
  __syncthreads();

  const int h = bh % NH;
  const float LOG2E = 1.4426950408889634f;
  const float sstd = sqrtf(wstd[h]);
  const float srec = sqrtf(wrec[h]);
  const half8_t hq_std = h8splat((_Float16)(0.125f * sstd * LOG2E));  // 1/sqrt(64) + log2e folded
  const half8_t hk_std = h8splat((_Float16)sstd);
  const half8_t hq_rec = h8splat((_Float16)(0.125f * srec * LOG2E));
  const half8_t hk_rec = h8splat((_Float16)srec);

  // premultiplied bias (log2 domain)
  if (tid < 64) B2[(long)bh*T_SEQ + tblk*64 + tid] =
      LOG2E * wdisc[h] * dbias[(long)bh*T_SEQ + tblk*64 + tid];

#pragma unroll
  for (int cc = 0; cc < 2; cc++) {
    int c = tid + cc * 256;                // chunk 0..511
    {
      int lp = c & 63, dp = (c >> 6) & 1, rt = c >> 7;
      int row = rt*16 + (lp & 15);
      int d0 = dp*32 + (lp >> 4)*8;        // 48-boundary on chunk boundary
      half8_t hq, hk;
      if (d0 < 48) {
        hq = *(const half8_t*)&Qsh[row*72 + d0] * hq_std;
        hk = *(const half8_t*)&Ksh[row*72 + d0] * hk_std;
      } else {
        hq = *(const half8_t*)&Lkh[row*16 + (d0-48)] * hq_rec;  // Q_aug gets K_low
        hk = *(const half8_t*)&Lqh[row*16 + (d0-48)] * hk_rec;  // K_aug gets Q_low
      }
      long tile16 = (long)bh*128 + tblk*4 + rt;
      ((int4*)QF)[tile16*128 + dp*64 + lp] = *(int4*)&hq;
      ((int4*)KF)[tile16*128 + dp*64 + lp] = *(int4*)&hk;
    }
    {
      int lv = c & 63, nt = (c >> 6) & 3, v2 = c >> 8;
      int d = nt*16 + (lv & 15), qv = lv >> 4;
      half8_t hv;
#pragma unroll
      for (int j = 0; j < 4; j++) {
        hv[j]   = Vsh[(v2*32 + qv*4 + j)*72 + d];
        hv[4+j] = Vsh[(v2*32 + 16 + qv*4 + j)*72 + d];
      }
      ((int4*)VF)[((long)bh*32 + tblk)*512 + (v2*4 + nt)*64 + lv] = *(int4*)&hv;
    }
  }
}

// ---------------- flash: 4 waves / block, one q-tile per wave, K/V shared via LDS ----------------
// R0 (12 w/CU) and R2 (24 w/CU) both pinned at 44 us with identical K/V L2 traffic
// (~810 MB/dispatch = ~30 B/cy/CU return BW) -> shared-throughput-bound on the K/V
// stream. R3's in-register 2-tile amortization spilled (105 MB scratch writes).
// Fix without register cost: block = 4 waves = q-tiles 4p..4p+3 (identical ktmax=p),
// K/V tile (16 KB) staged ONCE per block via global_load_lds, double-buffered,
// minimal 2-phase schedule (one __syncthreads per kt; its implicit vmcnt(0) drain
// is exactly the wait this schedule needs). Global K/V traffic drops 4x.
// kf/vf are now transient (LDS->reg right before use): VGPR pressure DROPS vs R2.
// launch_bounds (256,3): 3 blocks/CU co-resident, VGPR cap 170 (R1 lesson: never
// cap below ~register demand; watch FETCH/WRITE for spill).
__global__ __launch_bounds__(256, 3) void flash_kernel(
    const ushort* __restrict__ QF, const ushort* __restrict__ KF,
    const ushort* __restrict__ VF, const float* __restrict__ B2,
    float* __restrict__ Out)
{
  __shared__ __align__(16) _Float16 KV[2][2][4096];   // [buf][K|V][64 keys x 64 d], linear frag order

  const int tid  = threadIdx.x;
  const int wv   = tid >> 6;               // 0..3: q-tile within block
  const int lane = tid & 63;
  const int quad = lane >> 4, ln = lane & 15;
  const int bid = blockIdx.x;
  const int bh  = bid % BHC;               // same bh -> same XCD (24 % 8 == 0)
  const int p   = 31 - bid / BHC;          // heavy blocks first
  const int t16 = 4*p + wv;                // this wave's q-tile
  const int qrow = t16*16 + ln;            // this lane's q-row
  const int ktmax = p;                     // same for all 4 waves: floor((4p+w)/4)=p

  const ushort* gK = KF + (long)bh * 131072;   // halves
  const ushort* gV = VF + (long)bh * 131072;
  const float*  gB = B2 + (long)bh * T_SEQ;

  // Q B-frags (x32 layout: d = quad*8+j per 32-slice), whole K-loop in regs
  half8_t bq[2];
  {
    const ushort* gQ = QF + ((long)bh*128 + t16) * 1024;
    bq[0] = *(const half8_t*)(gQ + lane*8);
    bq[1] = *(const half8_t*)(gQ + 512 + lane*8);
  }

  float m_i = -1e30f, l_i = 0.f;
  floatx4 acc[4];
#pragma unroll
  for (int nt = 0; nt < 4; nt++) acc[nt] = (floatx4){0.f,0.f,0.f,0.f};

  // stage one 64-key K+V tile (16 chunks of 1 KB); wave w issues chunks w, w+4, w+8, w+12
  auto STAGE = [&](int nbuf, int kt) {
    const long tb = (long)kt * 4096;       // halves per 64-key tile (8 KB)
#pragma unroll
    for (int s = 0; s < 4; s++) {
      const int c = wv + s*4;              // 0..15; c<8 -> K, c>=8 -> V
      const ushort* src = (c < 8 ? gK + tb + c*512 : gV + tb + (c-8)*512) + lane*8;
      gload_lds16(src, &KV[nbuf][c>>3][(c&7)*512]);
    }
  };
  STAGE(0, 0);

  for (int kt = 0; kt <= ktmax; kt++) {
    const int cur = kt & 1;
    // barrier's implicit vmcnt(0) drain: tile kt fully landed in buf[cur];
    // all waves done reading buf[cur^1] -> safe to overwrite it next
    __syncthreads();
    if (kt < ktmax) STAGE(cur ^ 1, kt + 1);

    // bias registers (quad-uniform, shared keys across the block's q-tiles)
    float4 bb[4];
#pragma unroll
    for (int mt = 0; mt < 4; mt++)
      bb[mt] = *(const float4*)(gB + kt*64 + mt*16 + quad*4);

    // ---- S^T = K_aug·Q_aug^T (x32): st[mt][i] = S[q=ln][key=kt*64+mt*16+quad*4+i]
    half8_t kf[8];
#pragma unroll
    for (int c = 0; c < 8; c++)
      kf[c] = *(const half8_t*)&KV[cur][0][c*512 + lane*8];   // ds_read_b128, conflict-free
    floatx4 st[4];
#pragma unroll
    for (int mt = 0; mt < 4; mt++) {
      floatx4 c = (floatx4){0.f,0.f,0.f,0.f};
      c = __builtin_amdgcn_mfma_f32_16x16x32_f16(kf[mt*2],     bq[0], c, 0, 0, 0);
      c = __builtin_amdgcn_mfma_f32_16x16x32_f16(kf[mt*2 + 1], bq[1], c, 0, 0, 0);
      st[mt] = c;
    }

    // ---- bias + causal mask + online softmax, exp2 domain (one q-row per lane) ----
    const bool diag = (kt == ktmax);
    float rowmax = -1e30f;
#pragma unroll
    for (int mt = 0; mt < 4; mt++)
#pragma unroll
      for (int i = 0; i < 4; i++) {
        float v = st[mt][i] + ((const float*)&bb[mt])[i];
        int key = kt*64 + mt*16 + quad*4 + i;
        if (diag && key > qrow) v = -1e30f;
        st[mt][i] = v;
        rowmax = fmaxf(rowmax, v);
      }
    rowmax = fmaxf(rowmax, __shfl_xor(rowmax, 16));
    rowmax = fmaxf(rowmax, __shfl_xor(rowmax, 32));

    // defer-rescale: only pay the alpha broadcast + acc scale on a real max jump.
    // P stays bounded by 2^8 = 256, safe in f16; normalization cancels exactly.
    if (!__all(rowmax <= m_i + 8.f)) {
      float mnew  = fmaxf(m_i, rowmax);
      float alpha = exp2f(m_i - mnew);
      float af[4];
#pragma unroll
      for (int i = 0; i < 4; i++) af[i] = __shfl(alpha, quad*4 + i);
#pragma unroll
      for (int nt = 0; nt < 4; nt++)
#pragma unroll
        for (int i = 0; i < 4; i++) acc[nt][i] *= af[i];
      l_i *= alpha;
      m_i  = mnew;
    }

    float psum = 0.f;
    half4_t pa[4];                        // C-regs are directly the x16 PV A-operand
#pragma unroll
    for (int mt = 0; mt < 4; mt++)
#pragma unroll
      for (int i = 0; i < 4; i++) {
        float pv = exp2f(st[mt][i] - m_i);
        psum += pv;
        pa[mt][i] = (_Float16)pv;
      }
    psum += __shfl_xor(psum, 16);
    psum += __shfl_xor(psum, 32);
    l_i += psum;

    // ---- O += P·V (x16; P stays in registers) ----
#pragma unroll
    for (int v2 = 0; v2 < 2; v2++)
#pragma unroll
      for (int nt = 0; nt < 4; nt++) {
        half8_t vv = *(const half8_t*)&KV[cur][1][(v2*4 + nt)*512 + lane*8];
        half4_t b0 = __builtin_shufflevector(vv, vv, 0,1,2,3);
        half4_t b1 = __builtin_shufflevector(vv, vv, 4,5,6,7);
        acc[nt] = __builtin_amdgcn_mfma_f32_16x16x16f16(pa[2*v2],   b0, acc[nt], 0, 0, 0);
        acc[nt] = __builtin_amdgcn_mfma_f32_16x16x16f16(pa[2*v2+1], b1, acc[nt], 0, 0, 0);
      }
  }

  // ---- epilogue: each wave owns its full q-tile, direct write ----
  float lr[4];
#pragma unroll
  for (int i = 0; i < 4; i++) lr[i] = 1.f / __shfl(l_i, quad*4 + i);
  const long obase = (long)bh*T_SEQ*64 + (long)(t16*16)*64;
#pragma unroll
  for (int i = 0; i < 4; i++)
#pragma unroll
    for (int nt = 0; nt < 4; nt++)
      Out[obase + (quad*4 + i)*64 + nt*16 + ln] = acc[nt][i] * lr[i];
}

extern "C" void kernel_launch(void* const* d_in, const int* in_sizes, int n_in,
                              void* d_out, int out_size, void* d_ws, size_t ws_size,
                              hipStream_t stream) {
  const float* Q     = (const float*)d_in[0];
  const float* K     = (const float*)d_in[1];
  const float* V     = (const float*)d_in[2];
  const float* dbias = (const float*)d_in[3];
  const float* W     = (const float*)d_in[4];
  const float* wstd  = (const float*)d_in[5];
  const float* wrec  = (const float*)d_in[6];
  const float* wdisc = (const float*)d_in[7];
  float* Out = (float*)d_out;

  const long NEL = (long)BHC * T_SEQ * 64;
  ushort* QF = (ushort*)d_ws;            // f16 x32-frag-order Q_aug (scales+log2e folded)
  ushort* KF = QF + NEL;                 // f16 x32-frag-order K_aug
  ushort* VF = KF + NEL;                 // f16 x16-frag-order V
  float*  B2 = (float*)(VF + NEL);       // premultiplied wd*dbias*log2e

  prep_kernel<<<BHC * NQT, 256, 0, stream>>>(Q, K, V, W, wstd, wrec, dbias, wdisc,
                                             QF, KF, VF, B2);
  flash_kernel<<<BHC * 32, 256, 0, stream>>>(QF, KF, VF, B2, Out);
}